// Round 3
// baseline (161.251 us; speedup 1.0000x reference)
//
#include <hip/hip_runtime.h>

#define HH 128
#define WW 128
#define CIN 256
#define COUT 256
#define KTOT 2304   // 9 * 256, k = kk*256 + ci
#define HW (HH * WW)
#define NIT 36      // 9 taps * 4 channel-chunks of 64

typedef __attribute__((ext_vector_type(8))) short short8;
typedef __attribute__((ext_vector_type(4))) float f32x4;
typedef __attribute__((ext_vector_type(2))) float f32x2;

__device__ __forceinline__ unsigned rne_bf16(float f) {
  unsigned u = __float_as_uint(f);
  return (u + 0x7FFFu + ((u >> 16) & 1u)) >> 16;
}
__device__ __forceinline__ unsigned pack_bf16x2(float lo, float hi) {
  return rne_bf16(lo) | (rne_bf16(hi) << 16);
}
__device__ __forceinline__ unsigned cvt_pk_bf16(float lo, float hi) {
  unsigned r;
  asm("v_cvt_pk_bf16_f32 %0, %1, %2" : "=v"(r) : "v"(lo), "v"(hi));
  return r;
}
// unpack bf16x2 word -> {lo,hi} as exact f32 pair
__device__ __forceinline__ f32x2 up2(unsigned u) {
  f32x2 r;
  r.x = __uint_as_float(u << 16);
  r.y = __uint_as_float(u & 0xFFFF0000u);
  return r;
}
// packed dual-f32 mul/fma (weight pre-duplicated into both halves)
__device__ __forceinline__ f32x2 pkmul(f32x2 w, f32x2 v) {
  f32x2 d;
  asm("v_pk_mul_f32 %0, %1, %2" : "=v"(d) : "v"(w), "v"(v));
  return d;
}
__device__ __forceinline__ f32x2 pkfma(f32x2 w, f32x2 v, f32x2 c) {
  f32x2 d;
  asm("v_pk_fma_f32 %0, %1, %2, %3" : "=v"(d) : "v"(w), "v"(v), "v"(c));
  return d;
}

__device__ __forceinline__ void glds16(const void* g, void* l) {
  __builtin_amdgcn_global_load_lds(
      (const __attribute__((address_space(1))) void*)g,
      (__attribute__((address_space(3))) void*)l, 16, 0, 0);
}

// Merged prep: blocks [0,1024): x [N][CIN][H][W] fp32 -> xt [N][H][W][CIN] bf16
//              blocks [1024,3328): weight [COUT][CIN][3][3] -> wT [COUT][kk*256+ci]
__global__ void prep_inputs(const float* __restrict__ x, const float* __restrict__ wsrc,
                            unsigned short* __restrict__ xt, unsigned short* __restrict__ wT) {
  int b = blockIdx.x;
  __shared__ float tile[64][129];
  if (b < 1024) {
    int cg = b & 3;
    int nh = b >> 2;
    int n = nh >> 7, h = nh & 127;
    int c0 = cg << 6;
    const float* xp = x + ((size_t)n * CIN * HH + h) * WW;
    for (int e = threadIdx.x; e < 64 * 128; e += 256) {
      int w = e & 127, ci = e >> 7;
      tile[ci][w] = xp[(size_t)(c0 + ci) * HW + w];
    }
    __syncthreads();
    unsigned* dst = (unsigned*)(xt + ((size_t)(n * HH + h) * WW) * CIN + c0);
    for (int e = threadIdx.x; e < 128 * 32; e += 256) {
      int w = e >> 5, cp = e & 31;
      dst[w * (CIN / 2) + cp] = pack_bf16x2(tile[2 * cp][w], tile[2 * cp + 1][w]);
    }
  } else {
    int o = (b - 1024) * 256 + threadIdx.x;
    if (o >= COUT * KTOT) return;
    int co = o / KTOT;
    int r = o - co * KTOT;
    int kk = r >> 8, ci = r & 255;
    wT[o] = rne_bf16(wsrc[(size_t)(co * CIN + ci) * 9 + kk]);
  }
}

// R7: 4 waves, 64x64 wave tile (acc[4][4]); FULL double-buffer A+B (80KB LDS,
// 2 blocks/CU) -> ONE barrier/iter; counted vmcnt(8) keeps the 8 gather
// prefetches in flight across the barrier; per-thread obb params (no LDS);
// v_pk_fma_f32 blend; tap-rotation desync between block halves + setprio
// around MFMA so co-resident blocks overlap blend vs MFMA phases.
__global__ __launch_bounds__(256, 2) void fused_deform_gemm(
    const float* __restrict__ obb, const unsigned short* __restrict__ xt,
    const unsigned short* __restrict__ wT, float* __restrict__ out,
    const int* __restrict__ stride_p) {
  int g = blockIdx.x;
  int xcd = g & 7, li = g >> 3;
  int u = xcd * 64 + li;   // 0..511; each XCD gets a contiguous band
  int mh = u & 1;          // which half of the image row
  int bm = u >> 1;         // row id 0..255
  int n = bm >> 7, h = bm & 127;
  int tid = threadIdx.x;
  int phase = ((g >> 3) & 1) * 16;  // rotate start tap by 4 for half the blocks

  // 128B rows, physical byte = row*128 + (colbyte ^ ((row&7)<<4)); x2 buffers
  __shared__ __align__(16) unsigned short Alds[2][64 * 64];    // 16 KB
  __shared__ __align__(16) unsigned short Blds[2][256 * 64];   // 64 KB

  float inv_s = 1.0f / (float)stride_p[0];

  int lane = tid & 63;
  int wv = tid >> 6;          // 0..3
  int wn = wv * 64;           // wave cout base; wave tile = 64px x 64co
  int l15 = lane & 15, l4 = lane >> 4;

  // A-build: 8 lanes per pixel, one 16B (8-channel) chunk per thread; 2 jobs.
  int chunk8 = (lane & 7) * 8;
  int prow = wv * 8 + (lane >> 3);   // 0..31; jobs at pixels prow, 32+prow
  int AldsOff0 = prow * 128 + (((lane & 7) * 16) ^ ((prow & 7) << 4));

  // per-thread obb params (replaces LDS params; prow&7 == (lane>>3)&7)
  float cxj[2], cyj[2], paj[2], pbj[2], pcj[2], pdj[2];
#pragma unroll
  for (int j = 0; j < 2; ++j) {
    int p = j * 32 + prow;
    int w = mh * 64 + p;
    const float* op = obb + ((size_t)n * 5 * HH + h) * WW + w;
    float xc = op[0] * inv_s;
    float yc = op[(size_t)1 * HW] * inv_s;
    float bw = op[(size_t)2 * HW] * inv_s;
    float bh = op[(size_t)3 * HW] * inv_s;
    float th = op[(size_t)4 * HW];
    float sn, cs;
    sincosf(th, &sn, &cs);
    float dw = bw * (1.0f / 3.0f), dh = bh * (1.0f / 3.0f);
    cxj[j] = xc; cyj[j] = yc;
    paj[j] = dw * cs; pbj[j] = dh * sn;
    pcj[j] = dw * sn; pdj[j] = dh * cs;
  }

  f32x4 acc[4][4] = {};

  // B staging via global_load_lds: 8 instrs/wave/iter, rows t*32 + wv*8 + (lane>>3)
  int cbl = ((lane & 7) * 16) ^ (((lane >> 3) & 7) << 4);
  const char* wTb = (const char*)wT + (wv * 8 + (lane >> 3)) * (KTOT * 2) + cbl;

  // fragment-read column byte offsets (frag row &7 == l15&7)
  int rdXor = (l15 & 7) << 4;
  int rc0 = (l4 * 16) ^ rdXor;        // ks = 0
  int rc1 = (64 + l4 * 16) ^ rdXor;   // ks = 32

  f32x2 wgt2[2][4]; // bilinear weights (duplicated pairs) per job
  int boff[2][4];   // corner base element offsets per job
  uint4 pf[2][4];   // prefetched corner data (job, corner)
  uint4 aw[2];      // blended A chunks awaiting staging

  auto prep = [&](int kk) {
    float fky = (float)(kk / 3 - 1);
    float fkx = (float)(kk % 3 - 1);
#pragma unroll
    for (int j = 0; j < 2; ++j) {
      float sx = cxj[j] + fkx * paj[j] - fky * pbj[j];
      float sy = cyj[j] + fkx * pcj[j] + fky * pdj[j];
      float fx = floorf(sx), fy = floorf(sy);
      float lx = sx - fx, ly = sy - fy;
      int x0 = (int)fx, y0 = (int)fy;
      float vy0 = (y0 >= 0 && y0 < HH) ? 1.0f : 0.0f;
      float vy1 = (y0 >= -1 && y0 < HH - 1) ? 1.0f : 0.0f;
      float vx0 = (x0 >= 0 && x0 < WW) ? 1.0f : 0.0f;
      float vx1 = (x0 >= -1 && x0 < WW - 1) ? 1.0f : 0.0f;
      float w00 = (1.0f - ly) * (1.0f - lx) * vy0 * vx0;
      float w01 = (1.0f - ly) * lx * vy0 * vx1;
      float w10 = ly * (1.0f - lx) * vy1 * vx0;
      float w11 = ly * lx * vy1 * vx1;
      wgt2[j][0] = (f32x2){w00, w00};
      wgt2[j][1] = (f32x2){w01, w01};
      wgt2[j][2] = (f32x2){w10, w10};
      wgt2[j][3] = (f32x2){w11, w11};
      int xc0 = min(max(x0, 0), WW - 1), xc1 = min(max(x0 + 1, 0), WW - 1);
      int yc0 = min(max(y0, 0), HH - 1), yc1 = min(max(y0 + 1, 0), HH - 1);
      int rb0 = (n * HH + yc0) * WW, rb1 = (n * HH + yc1) * WW;
      boff[j][0] = (rb0 + xc0) * CIN;
      boff[j][1] = (rb0 + xc1) * CIN;
      boff[j][2] = (rb1 + xc0) * CIN;
      boff[j][3] = (rb1 + xc1) * CIN;
    }
  };

  auto issueA = [&](int cc) {
    int co = cc * 64 + chunk8;
#pragma unroll
    for (int j = 0; j < 2; ++j)
#pragma unroll
      for (int c = 0; c < 4; ++c)
        pf[j][c] = *(const uint4*)(xt + boff[j][c] + co);
  };

  auto blendW = [&](unsigned a, unsigned b, unsigned c, unsigned d, int j) -> unsigned {
    f32x2 s = pkmul(wgt2[j][0], up2(a));
    s = pkfma(wgt2[j][1], up2(b), s);
    s = pkfma(wgt2[j][2], up2(c), s);
    s = pkfma(wgt2[j][3], up2(d), s);
    return cvt_pk_bf16(s.x, s.y);
  };

  auto blendA = [&]() {
#pragma unroll
    for (int j = 0; j < 2; ++j) {
      uint4 r;
      r.x = blendW(pf[j][0].x, pf[j][1].x, pf[j][2].x, pf[j][3].x, j);
      r.y = blendW(pf[j][0].y, pf[j][1].y, pf[j][2].y, pf[j][3].y, j);
      r.z = blendW(pf[j][0].z, pf[j][1].z, pf[j][2].z, pf[j][3].z, j);
      r.w = blendW(pf[j][0].w, pf[j][1].w, pf[j][2].w, pf[j][3].w, j);
      aw[j] = r;
    }
  };

  char* AB = (char*)&Alds[0][0];
  char* BB = (char*)&Blds[0][0];

  // ---- prologue: stage k=phase into buf0; gathers for phase+1 in flight ----
  int kc = phase;
  prep(kc >> 2);
  issueA(kc & 3);
  blendA();
  *(uint4*)(AB + AldsOff0) = aw[0];
  *(uint4*)(AB + AldsOff0 + 4096) = aw[1];
  {
    char* Bd = BB + wv * 1024;
#pragma unroll
    for (int t = 0; t < 8; ++t)
      glds16(wTb + kc * 128 + t * (32 * KTOT * 2), Bd + t * 4096);
  }
  int nxt = kc + 1; if (nxt == NIT) nxt = 0;
  issueA(nxt & 3);   // phase&3==0 -> nxt&3==1, no prep needed
  asm volatile("s_waitcnt vmcnt(8) lgkmcnt(0)" ::: "memory");
  __builtin_amdgcn_s_barrier();
  asm volatile("" ::: "memory");

#pragma unroll 2
  for (int it = 0; it < NIT; ++it) {
    int buf = it & 1, nbuf = buf ^ 1;

    // ---- stage k=nxt into nbuf (glds first to hide L2 latency) ----
    if (it + 1 < NIT) {
      char* Bd = BB + nbuf * 32768 + wv * 1024;
#pragma unroll
      for (int t = 0; t < 8; ++t)
        glds16(wTb + nxt * 128 + t * (32 * KTOT * 2), Bd + t * 4096);
      blendA();   // consumes pf (gathers for nxt)
      *(uint4*)(AB + nbuf * 8192 + AldsOff0) = aw[0];
      *(uint4*)(AB + nbuf * 8192 + AldsOff0 + 4096) = aw[1];
      if (it + 2 < NIT) {
        int nn = nxt + 1; if (nn == NIT) nn = 0;
        if ((nn & 3) == 0) prep(nn >> 2);
        issueA(nn & 3);   // stays in flight across the barrier (vmcnt(8))
        nxt = nn;
      }
    }

    // ---- MFMA on buf ----
    char* ABr = AB + buf * 8192;
    char* BBr = BB + buf * 32768;
    __builtin_amdgcn_s_setprio(1);
#pragma unroll
    for (int ksi = 0; ksi < 2; ++ksi) {
      int rc = ksi ? rc1 : rc0;
      short8 af[4];
#pragma unroll
      for (int i = 0; i < 4; ++i)
        af[i] = *(const short8*)(ABr + (i * 16 + l15) * 128 + rc);
#pragma unroll
      for (int j = 0; j < 4; ++j) {
        short8 bf = *(const short8*)(BBr + (wn + j * 16 + l15) * 128 + rc);
#pragma unroll
        for (int i = 0; i < 4; ++i)
          acc[i][j] = __builtin_amdgcn_mfma_f32_16x16x32_bf16(af[i], bf, acc[i][j], 0, 0, 0);
      }
    }
    __builtin_amdgcn_s_setprio(0);

    // glds (weights) must land; the 8 newest vm-ops are next gathers - keep flying
    if (it < NIT - 2) {
      asm volatile("s_waitcnt vmcnt(8) lgkmcnt(0)" ::: "memory");
    } else {
      asm volatile("s_waitcnt vmcnt(0) lgkmcnt(0)" ::: "memory");
    }
    __builtin_amdgcn_s_barrier();
    asm volatile("" ::: "memory");
  }

  // ---- epilogue: out[n][co][h][w], float4 along w ----
  float* outp = out + (size_t)n * COUT * HW + (size_t)h * WW + mh * 64;
#pragma unroll
  for (int i = 0; i < 4; ++i) {
    int w0 = i * 16 + l4 * 4;
#pragma unroll
    for (int j = 0; j < 4; ++j) {
      int co = wn + j * 16 + l15;
      *(f32x4*)(outp + (size_t)co * HW + w0) = acc[i][j];
    }
  }
}

extern "C" void kernel_launch(void* const* d_in, const int* in_sizes, int n_in,
                              void* d_out, int out_size, void* d_ws, size_t ws_size,
                              hipStream_t stream) {
  const float* x = (const float*)d_in[0];
  const float* obb = (const float*)d_in[1];
  const float* wgt = (const float*)d_in[2];
  const int* stridep = (const int*)d_in[3];
  float* out = (float*)d_out;

  unsigned short* xt = (unsigned short*)d_ws;          // 2*128*128*256 bf16 = 16.8 MB
  unsigned short* wT = xt + (size_t)2 * HH * WW * CIN; // 256*2304 bf16 = 1.2 MB

  prep_inputs<<<dim3(1024 + 2304), 256, 0, stream>>>(x, wgt, xt, wT);
  fused_deform_gemm<<<dim3(512), 256, 0, stream>>>(obb, xt, wT, out, stridep);
}